// Round 1
// 1995.467 us; speedup vs baseline: 1.4199x; 1.4199x over previous
//
#include <hip/hip_runtime.h>

typedef unsigned int u32;

#define N_NODE_ 500
#define N_POD_  20000
#define N_SVC_  2000
#define N_TOT_  22500
#define T_ 16
#define F_ 64
#define H_ 128
#define O_ 64

// ---------------- static device scratch (no d_ws use) ----------------
// float region
#define OF_OUTD_SC  0
#define OF_IND_SC   2000
#define OF_OUTD_IN  4000
#define OF_IND_IN   24000
#define OF_OUTD_NI  24500
#define OF_IND_NI   25000
#define OF_OUTD_II  45000
#define OF_IND_II   65000
#define OF_OUTD_SI  85000
#define OF_IND_SI   87000
#define OF_OUTD_IS  107000
#define OF_IND_IS   127000
#define OF_DEG_END  129000
// LSTM weights, gate-interleaved transposed layout:
//   W[k][j][q] at offset k*256 + j*4 + q, value = W_orig[q*64 + j][k]
// OF_W0: [192][256]  (k<128: Wih0, k>=128: Whh0)
// OF_W1: [128][256]  (k<64:  Wih1, k>=64:  Whh1)
#define OF_W0       129024
#define OF_W1       (129024 + 49152)
#define G_F_SIZE    (129024 + 81920)
// int region (cnt doubles as fill cursor after re-zero)
#define OI_CNT_IN 0
#define OI_CNT_NI 500
#define OI_CNT_II 20500
#define OI_CNT_SI 40500
#define OI_CNT_SC 60500
#define OI_CNT_IS 62500
#define OI_CNT_END 64500
#define OI_OFF_IN 64500
#define OI_OFF_NI 65001
#define OI_OFF_II 85002
#define OI_OFF_SI 105003
#define OI_OFF_SC 125004
#define OI_OFF_IS 127005
#define OI_CSR_IN 129006
#define OI_CSR_NI 149006
#define OI_CSR_II 169006
#define OI_CSR_SI 269006
#define OI_CSR_SC 289006
#define OI_CSR_IS 305006
#define G_I_SIZE  325006

__device__ __align__(16) float g_f[G_F_SIZE];
__device__ int g_i[G_I_SIZE];

__device__ __forceinline__ float sigf(float x) { return 1.0f / (1.0f + __expf(-x)); }

__device__ __forceinline__ float f4c(const float4& v, int kk) {
  return kk == 0 ? v.x : kk == 1 ? v.y : kk == 2 ? v.z : v.w;
}

// ---------- zero the accumulated scratch regions (every launch) ----------
__global__ void zero_k() {
  int i = blockIdx.x * 256 + threadIdx.x;
  if (i < OF_DEG_END + 24) g_f[i] = 0.0f;
  if (i < OI_CNT_END) g_i[i] = 0;
}

__global__ void zero_cnt_k() {
  int i = blockIdx.x * 256 + threadIdx.x;
  if (i < OI_CNT_END) g_i[i] = 0;
}

// ---------- per-relation degrees + in-counts ----------
__global__ void deg_cnt_k(const int* __restrict__ src, const int* __restrict__ dst, int n,
                          int o_outd, int o_ind, int o_cnt) {
  int e = blockIdx.x * 256 + threadIdx.x;
  if (e < n) {
    atomicAdd(&g_f[o_outd + src[e]], 1.0f);
    atomicAdd(&g_f[o_ind + dst[e]], 1.0f);
    atomicAdd(&g_i[o_cnt + dst[e]], 1);
  }
}

__global__ void rsqrt_deg_k() {
  int i = blockIdx.x * 256 + threadIdx.x;
  if (i < OF_DEG_END) g_f[i] = rsqrtf(fmaxf(g_f[i], 1.0f));
}

// fp32 [256,K] (gate-major rows: i,f,g,o blocks of 64) -> gate-interleaved [K][64][4]
__global__ void transpose_w2_k(const float* __restrict__ in, int o_out, int K) {
  int i = blockIdx.x * 256 + threadIdx.x;
  if (i < 256 * K) {
    int r = i / K, k = i - r * K;
    int q = r >> 6, j = r & 63;
    g_f[o_out + k * 256 + (j << 2) + q] = in[i];
  }
}

// ---------- 6 single-block exclusive scans ----------
__global__ void exscan6_k() {
  const int cnto[6] = {OI_CNT_IN, OI_CNT_NI, OI_CNT_II, OI_CNT_SI, OI_CNT_SC, OI_CNT_IS};
  const int offo[6] = {OI_OFF_IN, OI_OFF_NI, OI_OFF_II, OI_OFF_SI, OI_OFF_SC, OI_OFF_IS};
  const int ns[6] = {500, 20000, 20000, 20000, 2000, 2000};
  int rel = blockIdx.x;
  const int* cnt = g_i + cnto[rel];
  int* off = g_i + offo[rel];
  int n = ns[rel];
  __shared__ int base_s[257];
  __shared__ int part[256];
  int tid = threadIdx.x;
  int chunk = (n + 255) >> 8;
  int lo = tid * chunk;
  int hi = lo + chunk; if (hi > n) hi = n;
  int s = 0;
  for (int i = lo; i < hi; ++i) s += cnt[i];
  part[tid] = s;
  __syncthreads();
  if (tid == 0) {
    int run = 0;
    for (int j = 0; j < 256; ++j) { base_s[j] = run; run += part[j]; }
    base_s[256] = run;
  }
  __syncthreads();
  int run = base_s[tid];
  for (int i = lo; i < hi; ++i) { off[i] = run; run += cnt[i]; }
  if (tid == 0) off[n] = base_s[256];
}

__global__ void fill_csr_k(const int* __restrict__ src, const int* __restrict__ dst, int n,
                           int o_off, int o_cur, int o_csr) {
  int e = blockIdx.x * 256 + threadIdx.x;
  if (e < n) {
    int d = dst[e];
    int p = atomicAdd(&g_i[o_cur + d], 1);
    g_i[o_csr + g_i[o_off + d] + p] = src[e];
  }
}

// ---------- fused gather + GEMM per dst node ----------
// block = one dst node; 256 threads; out[t][h] = relu(scale*(sum_rel m_rel*rsqrt(ind)*W_rel + b_rel))
template <int NREL>
__global__ __launch_bounds__(256) void gconv_gather_k(
    const float* __restrict__ x0, const float* __restrict__ x1, const float* __restrict__ x2,
    int off0, int off1, int off2, int csr0, int csr1, int csr2,
    int od0, int od1, int od2, int id0, int id1, int id2,
    const float* __restrict__ W0, const float* __restrict__ W1, const float* __restrict__ W2,
    const float* __restrict__ b0, const float* __restrict__ b1, const float* __restrict__ b2,
    float scale, float* __restrict__ outp) {
  const float* xs_[3] = {x0, x1, x2};
  const int offs[3] = {off0, off1, off2};
  const int csrs[3] = {csr0, csr1, csr2};
  const int ods[3] = {od0, od1, od2};
  const int ids[3] = {id0, id1, id2};
  const float* Ws[3] = {W0, W1, W2};
  const float* bs[3] = {b0, b1, b2};

  int node = blockIdx.x;
  int tid = threadIdx.x;
  int c = tid & 127;
  int rg = tid >> 7;  // 0/1 -> t rows [0,8) / [8,16)
  __shared__ float msh[T_][F_];  // flat index = t*64+f

  float bb = 0.0f;
#pragma unroll
  for (int rel = 0; rel < NREL; ++rel) bb += bs[rel][c];
  float acc[8];
#pragma unroll
  for (int i = 0; i < 8; ++i) acc[i] = bb;

#pragma unroll
  for (int rel = 0; rel < NREL; ++rel) {
    int e0 = g_i[offs[rel] + node], e1 = g_i[offs[rel] + node + 1];
    const int* csr = g_i + csrs[rel];
    const float* od = g_f + ods[rel];
    const float* xr = xs_[rel];
    // thread owns 4 contiguous elements of the 1024-float [T,F] row
    float a0 = 0.0f, a1 = 0.0f, a2 = 0.0f, a3 = 0.0f;
    for (int e = e0; e < e1; ++e) {
      int s = csr[e];
      float rs = od[s];
      float4 v = ((const float4*)(xr + (size_t)s * 1024))[tid];
      a0 += v.x * rs;
      a1 += v.y * rs;
      a2 += v.z * rs;
      a3 += v.w * rs;
    }
    __syncthreads();  // previous rel's GEMM reads done
    float* mf = &msh[0][0];
    mf[tid * 4 + 0] = a0;
    mf[tid * 4 + 1] = a1;
    mf[tid * 4 + 2] = a2;
    mf[tid * 4 + 3] = a3;
    __syncthreads();
    float rind = g_f[ids[rel] + node];
    const float* W = Ws[rel];
#pragma unroll 4
    for (int f = 0; f < F_; ++f) {
      float w = W[f * H_ + c] * rind;
#pragma unroll
      for (int i = 0; i < 8; ++i) acc[i] += msh[rg * 8 + i][f] * w;
    }
  }
  float* o = outp + (size_t)node * (T_ * H_);
#pragma unroll
  for (int i = 0; i < 8; ++i) {
    float v = acc[i] * scale;
    o[(rg * 8 + i) * H_ + c] = fmaxf(v, 0.0f);
  }
}

// ---------- 2-layer LSTM: register-tiled, barrier-free ----------
// Block = 32 rows, 256 threads = 4 waves = 8 independent 32-lane half-waves.
// Half-wave `grp` privately owns rows [blk*32 + grp*4, +4).
// Lane l (0..31) owns hidden units {l, l+32}; all 4 gates of a unit are
// in-thread (gate-interleaved W layout), so the cell update is lane-local
// and c-state lives in registers. Only h needs LDS (shared across the 32
// lanes of the half-wave); no __syncthreads anywhere.
__global__ __launch_bounds__(256, 3) void lstm_fast_k(
    const float* __restrict__ feat,  // [N_TOT,16,128] fp32 (post-relu)
    const float* __restrict__ bih0, const float* __restrict__ bhh0,
    const float* __restrict__ bih1, const float* __restrict__ bhh1,
    float* __restrict__ out2) {
  const float* W0 = g_f + OF_W0;  // [192][256]
  const float* W1 = g_f + OF_W1;  // [128][256]
  int tid = threadIdx.x;
  int l = tid & 31;    // lane within half-wave
  int grp = tid >> 5;  // 0..7
  int row0 = blockIdx.x * 32 + grp * 4;
  int lr0 = grp * 4;

  // cols 0..63 = h(layer0), 64..127 = h(layer1)
  __shared__ __align__(16) float hs[32][128];

#pragma unroll
  for (int r = 0; r < 4; ++r) {
    hs[lr0 + r][l] = 0.0f;
    hs[lr0 + r][l + 32] = 0.0f;
    hs[lr0 + r][l + 64] = 0.0f;
    hs[lr0 + r][l + 96] = 0.0f;
  }

  float c0[4][2] = {}, c1[4][2] = {};
  float bb0[2][4], bb1[2][4];
#pragma unroll
  for (int jj = 0; jj < 2; ++jj)
#pragma unroll
    for (int q = 0; q < 4; ++q) {
      int col = q * 64 + l + jj * 32;
      bb0[jj][q] = bih0[col] + bhh0[col];
      bb1[jj][q] = bih1[col] + bhh1[col];
    }

  bool vld[4];
  const float* xb[4];
#pragma unroll
  for (int r = 0; r < 4; ++r) {
    int row = row0 + r;
    vld[r] = row < N_TOT_;
    // clamp invalid rows to row 0: loads stay in-bounds, results discarded
    xb[r] = feat + (size_t)(vld[r] ? row : 0) * (T_ * H_);
  }

  for (int t = 0; t < T_; ++t) {
    float acc[4][2][4];
#pragma unroll
    for (int r = 0; r < 4; ++r)
#pragma unroll
      for (int jj = 0; jj < 2; ++jj)
#pragma unroll
        for (int q = 0; q < 4; ++q) acc[r][jj][q] = bb0[jj][q];

    // ---- layer 0: x_t @ Wih0  (K=128, x broadcast from global) ----
    {
      const float* x0p = xb[0] + t * H_;
      const float* x1p = xb[1] + t * H_;
      const float* x2p = xb[2] + t * H_;
      const float* x3p = xb[3] + t * H_;
      for (int k = 0; k < 128; k += 4) {
        float4 xv[4];
        xv[0] = *(const float4*)(x0p + k);
        xv[1] = *(const float4*)(x1p + k);
        xv[2] = *(const float4*)(x2p + k);
        xv[3] = *(const float4*)(x3p + k);
        const float* wkb = W0 + (k << 8) + (l << 2);
        float4 wa[4], wb[4];
#pragma unroll
        for (int kk = 0; kk < 4; ++kk) {
          wa[kk] = *(const float4*)(wkb + (kk << 8));
          wb[kk] = *(const float4*)(wkb + (kk << 8) + 128);
        }
#pragma unroll
        for (int kk = 0; kk < 4; ++kk) {
          float wv[2][4] = {{wa[kk].x, wa[kk].y, wa[kk].z, wa[kk].w},
                            {wb[kk].x, wb[kk].y, wb[kk].z, wb[kk].w}};
#pragma unroll
          for (int r = 0; r < 4; ++r) {
            float x = f4c(xv[r], kk);
#pragma unroll
            for (int jj = 0; jj < 2; ++jj)
#pragma unroll
              for (int q = 0; q < 4; ++q) acc[r][jj][q] += x * wv[jj][q];
          }
        }
      }
    }
    // ---- layer 0: h0_prev @ Whh0  (K=64, h broadcast from LDS) ----
    for (int k = 0; k < 64; k += 4) {
      float4 hv[4];
#pragma unroll
      for (int r = 0; r < 4; ++r) hv[r] = *(const float4*)(&hs[lr0 + r][k]);
      const float* wkb = W0 + ((128 + k) << 8) + (l << 2);
      float4 wa[4], wb[4];
#pragma unroll
      for (int kk = 0; kk < 4; ++kk) {
        wa[kk] = *(const float4*)(wkb + (kk << 8));
        wb[kk] = *(const float4*)(wkb + (kk << 8) + 128);
      }
#pragma unroll
      for (int kk = 0; kk < 4; ++kk) {
        float wv[2][4] = {{wa[kk].x, wa[kk].y, wa[kk].z, wa[kk].w},
                          {wb[kk].x, wb[kk].y, wb[kk].z, wb[kk].w}};
#pragma unroll
        for (int r = 0; r < 4; ++r) {
          float x = f4c(hv[r], kk);
#pragma unroll
          for (int jj = 0; jj < 2; ++jj)
#pragma unroll
            for (int q = 0; q < 4; ++q) acc[r][jj][q] += x * wv[jj][q];
        }
      }
    }
    // ---- layer 0 cell update (lane-local), h0_new -> LDS ----
    __builtin_amdgcn_wave_barrier();  // keep h0_prev reads above the writes
#pragma unroll
    for (int r = 0; r < 4; ++r)
#pragma unroll
      for (int jj = 0; jj < 2; ++jj) {
        float iv = sigf(acc[r][jj][0]);
        float fv = sigf(acc[r][jj][1]);
        float gv = tanhf(acc[r][jj][2]);
        float ov = sigf(acc[r][jj][3]);
        float cc = fv * c0[r][jj] + iv * gv;
        c0[r][jj] = cc;
        hs[lr0 + r][l + jj * 32] = ov * tanhf(cc);
      }
    __builtin_amdgcn_wave_barrier();  // h0_new writes complete before L1 reads

    // ---- layer 1: [h0_new | h1_prev] @ [Wih1 | Whh1]  (K=128 from LDS) ----
#pragma unroll
    for (int r = 0; r < 4; ++r)
#pragma unroll
      for (int jj = 0; jj < 2; ++jj)
#pragma unroll
        for (int q = 0; q < 4; ++q) acc[r][jj][q] = bb1[jj][q];
    for (int k = 0; k < 128; k += 4) {
      float4 hv[4];
#pragma unroll
      for (int r = 0; r < 4; ++r) hv[r] = *(const float4*)(&hs[lr0 + r][k]);
      const float* wkb = W1 + (k << 8) + (l << 2);
      float4 wa[4], wb[4];
#pragma unroll
      for (int kk = 0; kk < 4; ++kk) {
        wa[kk] = *(const float4*)(wkb + (kk << 8));
        wb[kk] = *(const float4*)(wkb + (kk << 8) + 128);
      }
#pragma unroll
      for (int kk = 0; kk < 4; ++kk) {
        float wv[2][4] = {{wa[kk].x, wa[kk].y, wa[kk].z, wa[kk].w},
                          {wb[kk].x, wb[kk].y, wb[kk].z, wb[kk].w}};
#pragma unroll
        for (int r = 0; r < 4; ++r) {
          float x = f4c(hv[r], kk);
#pragma unroll
          for (int jj = 0; jj < 2; ++jj)
#pragma unroll
            for (int q = 0; q < 4; ++q) acc[r][jj][q] += x * wv[jj][q];
        }
      }
    }
    // ---- layer 1 cell update, h1_new -> LDS + relu -> global ----
    __builtin_amdgcn_wave_barrier();  // keep h1_prev reads above the writes
#pragma unroll
    for (int r = 0; r < 4; ++r)
#pragma unroll
      for (int jj = 0; jj < 2; ++jj) {
        float iv = sigf(acc[r][jj][0]);
        float fv = sigf(acc[r][jj][1]);
        float gv = tanhf(acc[r][jj][2]);
        float ov = sigf(acc[r][jj][3]);
        float cc = fv * c1[r][jj] + iv * gv;
        c1[r][jj] = cc;
        float hh = ov * tanhf(cc);
        hs[lr0 + r][64 + l + jj * 32] = hh;
        if (vld[r]) out2[((size_t)(row0 + r) * T_ + t) * O_ + l + jj * 32] = fmaxf(hh, 0.0f);
      }
    __builtin_amdgcn_wave_barrier();  // h1_new writes complete before next-t reads
  }
}

extern "C" void kernel_launch(void* const* d_in, const int* in_sizes, int n_in,
                              void* d_out, int out_size, void* d_ws, size_t ws_size,
                              hipStream_t stream) {
  (void)in_sizes; (void)n_in; (void)out_size; (void)d_ws; (void)ws_size;
  const float* x_node = (const float*)d_in[0];
  const float* x_pod  = (const float*)d_in[1];
  const float* x_svc  = (const float*)d_in[2];
  const int* sc_src = (const int*)d_in[3];
  const int* sc_dst = (const int*)d_in[4];
  const int* in_src = (const int*)d_in[5];
  const int* in_dst = (const int*)d_in[6];
  const int* ni_src = (const int*)d_in[7];
  const int* ni_dst = (const int*)d_in[8];
  const int* ii_src = (const int*)d_in[9];
  const int* ii_dst = (const int*)d_in[10];
  const int* si_src = (const int*)d_in[11];
  const int* si_dst = (const int*)d_in[12];
  const int* is_src = (const int*)d_in[13];
  const int* is_dst = (const int*)d_in[14];
  const float* W_sc = (const float*)d_in[15]; const float* b_sc = (const float*)d_in[16];
  const float* W_in = (const float*)d_in[17]; const float* b_in = (const float*)d_in[18];
  const float* W_ni = (const float*)d_in[19]; const float* b_ni = (const float*)d_in[20];
  const float* W_ii = (const float*)d_in[21]; const float* b_ii = (const float*)d_in[22];
  const float* W_si = (const float*)d_in[23]; const float* b_si = (const float*)d_in[24];
  const float* W_is = (const float*)d_in[25]; const float* b_is = (const float*)d_in[26];
  const float* Wih0 = (const float*)d_in[27]; const float* Whh0 = (const float*)d_in[28];
  const float* bih0 = (const float*)d_in[29]; const float* bhh0 = (const float*)d_in[30];
  const float* Wih1 = (const float*)d_in[31]; const float* Whh1 = (const float*)d_in[32];
  const float* bih1 = (const float*)d_in[33]; const float* bhh1 = (const float*)d_in[34];

  float* out_feat = (float*)d_out;
  float* out_h = out_feat + (size_t)N_TOT_ * T_ * H_;  // +46,080,000

  // zero accumulated scratch
  zero_k<<<(OF_DEG_END + 24 + 255) / 256, 256, 0, stream>>>();

  // degrees + counts
  deg_cnt_k<<<(16000 + 255) / 256, 256, 0, stream>>>(sc_src, sc_dst, 16000, OF_OUTD_SC, OF_IND_SC, OI_CNT_SC);
  deg_cnt_k<<<(20000 + 255) / 256, 256, 0, stream>>>(in_src, in_dst, 20000, OF_OUTD_IN, OF_IND_IN, OI_CNT_IN);
  deg_cnt_k<<<(20000 + 255) / 256, 256, 0, stream>>>(ni_src, ni_dst, 20000, OF_OUTD_NI, OF_IND_NI, OI_CNT_NI);
  deg_cnt_k<<<(100000 + 255) / 256, 256, 0, stream>>>(ii_src, ii_dst, 100000, OF_OUTD_II, OF_IND_II, OI_CNT_II);
  deg_cnt_k<<<(20000 + 255) / 256, 256, 0, stream>>>(si_src, si_dst, 20000, OF_OUTD_SI, OF_IND_SI, OI_CNT_SI);
  deg_cnt_k<<<(20000 + 255) / 256, 256, 0, stream>>>(is_src, is_dst, 20000, OF_OUTD_IS, OF_IND_IS, OI_CNT_IS);
  rsqrt_deg_k<<<(OF_DEG_END + 255) / 256, 256, 0, stream>>>();

  // LSTM weight transposes into gate-interleaved [k][j][4] layout
  transpose_w2_k<<<(256 * 128 + 255) / 256, 256, 0, stream>>>(Wih0, OF_W0, 128);
  transpose_w2_k<<<(256 * 64 + 255) / 256, 256, 0, stream>>>(Whh0, OF_W0 + 128 * 256, 64);
  transpose_w2_k<<<(256 * 64 + 255) / 256, 256, 0, stream>>>(Wih1, OF_W1, 64);
  transpose_w2_k<<<(256 * 64 + 255) / 256, 256, 0, stream>>>(Whh1, OF_W1 + 64 * 256, 64);

  // CSR build
  exscan6_k<<<6, 256, 0, stream>>>();
  zero_cnt_k<<<(OI_CNT_END + 255) / 256, 256, 0, stream>>>();
  fill_csr_k<<<(20000 + 255) / 256, 256, 0, stream>>>(in_src, in_dst, 20000, OI_OFF_IN, OI_CNT_IN, OI_CSR_IN);
  fill_csr_k<<<(20000 + 255) / 256, 256, 0, stream>>>(ni_src, ni_dst, 20000, OI_OFF_NI, OI_CNT_NI, OI_CSR_NI);
  fill_csr_k<<<(100000 + 255) / 256, 256, 0, stream>>>(ii_src, ii_dst, 100000, OI_OFF_II, OI_CNT_II, OI_CSR_II);
  fill_csr_k<<<(20000 + 255) / 256, 256, 0, stream>>>(si_src, si_dst, 20000, OI_OFF_SI, OI_CNT_SI, OI_CSR_SI);
  fill_csr_k<<<(16000 + 255) / 256, 256, 0, stream>>>(sc_src, sc_dst, 16000, OI_OFF_SC, OI_CNT_SC, OI_CSR_SC);
  fill_csr_k<<<(20000 + 255) / 256, 256, 0, stream>>>(is_src, is_dst, 20000, OI_OFF_IS, OI_CNT_IS, OI_CSR_IS);

  // fused gather + GEMM per dst type
  gconv_gather_k<1><<<N_NODE_, 256, 0, stream>>>(
      x_pod, nullptr, nullptr, OI_OFF_IN, 0, 0, OI_CSR_IN, 0, 0,
      OF_OUTD_IN, 0, 0, OF_IND_IN, 0, 0,
      W_in, nullptr, nullptr, b_in, nullptr, nullptr, 1.0f, out_feat);
  gconv_gather_k<3><<<N_POD_, 256, 0, stream>>>(
      x_node, x_pod, x_svc, OI_OFF_NI, OI_OFF_II, OI_OFF_SI, OI_CSR_NI, OI_CSR_II, OI_CSR_SI,
      OF_OUTD_NI, OF_OUTD_II, OF_OUTD_SI, OF_IND_NI, OF_IND_II, OF_IND_SI,
      W_ni, W_ii, W_si, b_ni, b_ii, b_si, 1.0f / 3.0f,
      out_feat + (size_t)N_NODE_ * (T_ * H_));
  gconv_gather_k<2><<<N_SVC_, 256, 0, stream>>>(
      x_svc, x_pod, nullptr, OI_OFF_SC, OI_OFF_IS, 0, OI_CSR_SC, OI_CSR_IS, 0,
      OF_OUTD_SC, OF_OUTD_IS, 0, OF_IND_SC, OF_IND_IS, 0,
      W_sc, W_is, nullptr, b_sc, b_is, nullptr, 0.5f,
      out_feat + (size_t)(N_NODE_ + N_POD_) * (T_ * H_));

  // 2-layer LSTM, register-tiled, barrier-free
  lstm_fast_k<<<(N_TOT_ + 31) / 32, 256, 0, stream>>>(
      out_feat, bih0, bhh0, bih1, bhh1, out_h);
}

// Round 2
// 1815.579 us; speedup vs baseline: 1.5606x; 1.0991x over previous
//
#include <hip/hip_runtime.h>

typedef unsigned int u32;

#define N_NODE_ 500
#define N_POD_  20000
#define N_SVC_  2000
#define N_TOT_  22500
#define T_ 16
#define F_ 64
#define H_ 128
#define O_ 64

// ---------------- static device scratch (no d_ws use) ----------------
// float region
#define OF_OUTD_SC  0
#define OF_IND_SC   2000
#define OF_OUTD_IN  4000
#define OF_IND_IN   24000
#define OF_OUTD_NI  24500
#define OF_IND_NI   25000
#define OF_OUTD_II  45000
#define OF_IND_II   65000
#define OF_OUTD_SI  85000
#define OF_IND_SI   87000
#define OF_OUTD_IS  107000
#define OF_IND_IS   127000
#define OF_DEG_END  129000
// LSTM weights, gate-interleaved transposed layout:
//   W[k][j][q] at offset k*256 + j*4 + q, value = W_orig[q*64 + j][k]
// OF_W0: [192][256]  (k<128: Wih0, k>=128: Whh0)
// OF_W1: [128][256]  (k<64:  Wih1, k>=64:  Whh1)
#define OF_W0       129024
#define OF_W1       (129024 + 49152)
#define G_F_SIZE    (129024 + 81920)
// int region (cnt doubles as fill cursor after re-zero)
#define OI_CNT_IN 0
#define OI_CNT_NI 500
#define OI_CNT_II 20500
#define OI_CNT_SI 40500
#define OI_CNT_SC 60500
#define OI_CNT_IS 62500
#define OI_CNT_END 64500
#define OI_OFF_IN 64500
#define OI_OFF_NI 65001
#define OI_OFF_II 85002
#define OI_OFF_SI 105003
#define OI_OFF_SC 125004
#define OI_OFF_IS 127005
#define OI_CSR_IN 129006
#define OI_CSR_NI 149006
#define OI_CSR_II 169006
#define OI_CSR_SI 269006
#define OI_CSR_SC 289006
#define OI_CSR_IS 305006
#define G_I_SIZE  325006

__device__ __align__(16) float g_f[G_F_SIZE];
__device__ int g_i[G_I_SIZE];

__device__ __forceinline__ float sigf(float x) { return 1.0f / (1.0f + __expf(-x)); }

// broadcast register value from lane k (k uniform) via v_readlane -> SGPR
__device__ __forceinline__ float rlane(float v, int k) {
  return __uint_as_float(__builtin_amdgcn_readlane(__float_as_uint(v), k));
}

// ---------- zero the accumulated scratch regions (every launch) ----------
__global__ void zero_k() {
  int i = blockIdx.x * 256 + threadIdx.x;
  if (i < OF_DEG_END + 24) g_f[i] = 0.0f;
  if (i < OI_CNT_END) g_i[i] = 0;
}

__global__ void zero_cnt_k() {
  int i = blockIdx.x * 256 + threadIdx.x;
  if (i < OI_CNT_END) g_i[i] = 0;
}

// ---------- per-relation degrees + in-counts ----------
__global__ void deg_cnt_k(const int* __restrict__ src, const int* __restrict__ dst, int n,
                          int o_outd, int o_ind, int o_cnt) {
  int e = blockIdx.x * 256 + threadIdx.x;
  if (e < n) {
    atomicAdd(&g_f[o_outd + src[e]], 1.0f);
    atomicAdd(&g_f[o_ind + dst[e]], 1.0f);
    atomicAdd(&g_i[o_cnt + dst[e]], 1);
  }
}

__global__ void rsqrt_deg_k() {
  int i = blockIdx.x * 256 + threadIdx.x;
  if (i < OF_DEG_END) g_f[i] = rsqrtf(fmaxf(g_f[i], 1.0f));
}

// fp32 [256,K] (gate-major rows: i,f,g,o blocks of 64) -> gate-interleaved [K][64][4]
__global__ void transpose_w2_k(const float* __restrict__ in, int o_out, int K) {
  int i = blockIdx.x * 256 + threadIdx.x;
  if (i < 256 * K) {
    int r = i / K, k = i - r * K;
    int q = r >> 6, j = r & 63;
    g_f[o_out + k * 256 + (j << 2) + q] = in[i];
  }
}

// ---------- 6 single-block exclusive scans ----------
__global__ void exscan6_k() {
  const int cnto[6] = {OI_CNT_IN, OI_CNT_NI, OI_CNT_II, OI_CNT_SI, OI_CNT_SC, OI_CNT_IS};
  const int offo[6] = {OI_OFF_IN, OI_OFF_NI, OI_OFF_II, OI_OFF_SI, OI_OFF_SC, OI_OFF_IS};
  const int ns[6] = {500, 20000, 20000, 20000, 2000, 2000};
  int rel = blockIdx.x;
  const int* cnt = g_i + cnto[rel];
  int* off = g_i + offo[rel];
  int n = ns[rel];
  __shared__ int base_s[257];
  __shared__ int part[256];
  int tid = threadIdx.x;
  int chunk = (n + 255) >> 8;
  int lo = tid * chunk;
  int hi = lo + chunk; if (hi > n) hi = n;
  int s = 0;
  for (int i = lo; i < hi; ++i) s += cnt[i];
  part[tid] = s;
  __syncthreads();
  if (tid == 0) {
    int run = 0;
    for (int j = 0; j < 256; ++j) { base_s[j] = run; run += part[j]; }
    base_s[256] = run;
  }
  __syncthreads();
  int run = base_s[tid];
  for (int i = lo; i < hi; ++i) { off[i] = run; run += cnt[i]; }
  if (tid == 0) off[n] = base_s[256];
}

__global__ void fill_csr_k(const int* __restrict__ src, const int* __restrict__ dst, int n,
                           int o_off, int o_cur, int o_csr) {
  int e = blockIdx.x * 256 + threadIdx.x;
  if (e < n) {
    int d = dst[e];
    int p = atomicAdd(&g_i[o_cur + d], 1);
    g_i[o_csr + g_i[o_off + d] + p] = src[e];
  }
}

// ---------- fused gather + GEMM per dst node ----------
// block = one dst node; 256 threads; out[t][h] = relu(scale*(sum_rel m_rel*rsqrt(ind)*W_rel + b_rel))
template <int NREL>
__global__ __launch_bounds__(256) void gconv_gather_k(
    const float* __restrict__ x0, const float* __restrict__ x1, const float* __restrict__ x2,
    int off0, int off1, int off2, int csr0, int csr1, int csr2,
    int od0, int od1, int od2, int id0, int id1, int id2,
    const float* __restrict__ W0, const float* __restrict__ W1, const float* __restrict__ W2,
    const float* __restrict__ b0, const float* __restrict__ b1, const float* __restrict__ b2,
    float scale, float* __restrict__ outp) {
  const float* xs_[3] = {x0, x1, x2};
  const int offs[3] = {off0, off1, off2};
  const int csrs[3] = {csr0, csr1, csr2};
  const int ods[3] = {od0, od1, od2};
  const int ids[3] = {id0, id1, id2};
  const float* Ws[3] = {W0, W1, W2};
  const float* bs[3] = {b0, b1, b2};

  int node = blockIdx.x;
  int tid = threadIdx.x;
  int c = tid & 127;
  int rg = tid >> 7;  // 0/1 -> t rows [0,8) / [8,16)
  __shared__ float msh[T_][F_];  // flat index = t*64+f

  float bb = 0.0f;
#pragma unroll
  for (int rel = 0; rel < NREL; ++rel) bb += bs[rel][c];
  float acc[8];
#pragma unroll
  for (int i = 0; i < 8; ++i) acc[i] = bb;

#pragma unroll
  for (int rel = 0; rel < NREL; ++rel) {
    int e0 = g_i[offs[rel] + node], e1 = g_i[offs[rel] + node + 1];
    const int* csr = g_i + csrs[rel];
    const float* od = g_f + ods[rel];
    const float* xr = xs_[rel];
    // thread owns 4 contiguous elements of the 1024-float [T,F] row
    float a0 = 0.0f, a1 = 0.0f, a2 = 0.0f, a3 = 0.0f;
    for (int e = e0; e < e1; ++e) {
      int s = csr[e];
      float rs = od[s];
      float4 v = ((const float4*)(xr + (size_t)s * 1024))[tid];
      a0 += v.x * rs;
      a1 += v.y * rs;
      a2 += v.z * rs;
      a3 += v.w * rs;
    }
    __syncthreads();  // previous rel's GEMM reads done
    float* mf = &msh[0][0];
    mf[tid * 4 + 0] = a0;
    mf[tid * 4 + 1] = a1;
    mf[tid * 4 + 2] = a2;
    mf[tid * 4 + 3] = a3;
    __syncthreads();
    float rind = g_f[ids[rel] + node];
    const float* W = Ws[rel];
#pragma unroll 4
    for (int f = 0; f < F_; ++f) {
      float w = W[f * H_ + c] * rind;
#pragma unroll
      for (int i = 0; i < 8; ++i) acc[i] += msh[rg * 8 + i][f] * w;
    }
  }
  float* o = outp + (size_t)node * (T_ * H_);
#pragma unroll
  for (int i = 0; i < 8; ++i) {
    float v = acc[i] * scale;
    o[(rg * 8 + i) * H_ + c] = fmaxf(v, 0.0f);
  }
}

// ---------- 2-layer LSTM: fully register-resident, readlane-broadcast ----------
// Grid: 512 blocks x 256 threads (4 waves) = 2048 independent waves, 11 rows each
// (512*4*11 = 22528 >= 22500). Exactly 2 blocks/CU -> 8 waves/CU, balanced.
// Mapping: lane l owns hidden unit j=l (all 4 gates, cols q*64+l). So h and c
// are single per-lane registers; no LDS, no barriers. The row-broadcast operand
// (x_t or h_prev) is distributed across lanes (element k lives in lane k) and
// broadcast via v_readlane with the uniform loop index -> SGPR operand of the
// FMA. W is streamed from global as one coalesced float4 per k per lane
// (gate-interleaved layout [k][j][4]).
#define RW 11  // rows per wave

__device__ __forceinline__ void gemv64(float acc[RW][4], const float src[RW],
                                       const float4* __restrict__ Wb, int l) {
#pragma unroll 4
  for (int k = 0; k < 64; ++k) {
    float4 w = Wb[(k << 6) + l];
#pragma unroll
    for (int r = 0; r < RW; ++r) {
      float s = rlane(src[r], k);
      acc[r][0] += s * w.x;
      acc[r][1] += s * w.y;
      acc[r][2] += s * w.z;
      acc[r][3] += s * w.w;
    }
  }
}

__global__ __launch_bounds__(256, 2) void lstm_reg_k(
    const float* __restrict__ feat,  // [N_TOT,16,128] fp32 (post-relu)
    const float* __restrict__ bih0, const float* __restrict__ bhh0,
    const float* __restrict__ bih1, const float* __restrict__ bhh1,
    float* __restrict__ out2) {
  const float4* W0v = (const float4*)(g_f + OF_W0);  // [192][64] float4
  const float4* W1v = (const float4*)(g_f + OF_W1);  // [128][64] float4
  int tid = threadIdx.x;
  int l = tid & 63;
  int wid = tid >> 6;
  int row0 = (blockIdx.x * 4 + wid) * RW;

  float bb0[4], bb1[4];
#pragma unroll
  for (int q = 0; q < 4; ++q) {
    bb0[q] = bih0[q * 64 + l] + bhh0[q * 64 + l];
    bb1[q] = bih1[q * 64 + l] + bhh1[q * 64 + l];
  }

  const float* xb[RW];
  bool vld[RW];
#pragma unroll
  for (int r = 0; r < RW; ++r) {
    int row = row0 + r;
    vld[r] = row < N_TOT_;
    xb[r] = feat + (size_t)(vld[r] ? row : 0) * (T_ * H_);
  }

  float h0[RW] = {}, c0[RW] = {}, h1[RW] = {}, c1[RW] = {};

  for (int t = 0; t < T_; ++t) {
    // stage x_t into registers: element k of row r lives in lane k (lo/hi half)
    float xlo[RW], xhi[RW];
#pragma unroll
    for (int r = 0; r < RW; ++r) {
      xlo[r] = xb[r][t * H_ + l];
      xhi[r] = xb[r][t * H_ + 64 + l];
    }

    float acc[RW][4];
#pragma unroll
    for (int r = 0; r < RW; ++r)
#pragma unroll
      for (int q = 0; q < 4; ++q) acc[r][q] = bb0[q];

    // layer 0: x_t @ Wih0 (K=128) + h0_prev @ Whh0 (K=64)
    gemv64(acc, xlo, W0v, l);
    gemv64(acc, xhi, W0v + 64 * 64, l);
    gemv64(acc, h0, W0v + 128 * 64, l);

#pragma unroll
    for (int r = 0; r < RW; ++r) {
      float iv = sigf(acc[r][0]);
      float fv = sigf(acc[r][1]);
      float gv = tanhf(acc[r][2]);
      float ov = sigf(acc[r][3]);
      float cc = fv * c0[r] + iv * gv;
      c0[r] = cc;
      h0[r] = ov * tanhf(cc);
    }

#pragma unroll
    for (int r = 0; r < RW; ++r)
#pragma unroll
      for (int q = 0; q < 4; ++q) acc[r][q] = bb1[q];

    // layer 1: h0_new @ Wih1 (K=64) + h1_prev @ Whh1 (K=64)
    gemv64(acc, h0, W1v, l);
    gemv64(acc, h1, W1v + 64 * 64, l);

#pragma unroll
    for (int r = 0; r < RW; ++r) {
      float iv = sigf(acc[r][0]);
      float fv = sigf(acc[r][1]);
      float gv = tanhf(acc[r][2]);
      float ov = sigf(acc[r][3]);
      float cc = fv * c1[r] + iv * gv;
      c1[r] = cc;
      float hh = ov * tanhf(cc);
      h1[r] = hh;
      if (vld[r]) out2[((size_t)(row0 + r) * T_ + t) * O_ + l] = fmaxf(hh, 0.0f);
    }
  }
}

extern "C" void kernel_launch(void* const* d_in, const int* in_sizes, int n_in,
                              void* d_out, int out_size, void* d_ws, size_t ws_size,
                              hipStream_t stream) {
  (void)in_sizes; (void)n_in; (void)out_size; (void)d_ws; (void)ws_size;
  const float* x_node = (const float*)d_in[0];
  const float* x_pod  = (const float*)d_in[1];
  const float* x_svc  = (const float*)d_in[2];
  const int* sc_src = (const int*)d_in[3];
  const int* sc_dst = (const int*)d_in[4];
  const int* in_src = (const int*)d_in[5];
  const int* in_dst = (const int*)d_in[6];
  const int* ni_src = (const int*)d_in[7];
  const int* ni_dst = (const int*)d_in[8];
  const int* ii_src = (const int*)d_in[9];
  const int* ii_dst = (const int*)d_in[10];
  const int* si_src = (const int*)d_in[11];
  const int* si_dst = (const int*)d_in[12];
  const int* is_src = (const int*)d_in[13];
  const int* is_dst = (const int*)d_in[14];
  const float* W_sc = (const float*)d_in[15]; const float* b_sc = (const float*)d_in[16];
  const float* W_in = (const float*)d_in[17]; const float* b_in = (const float*)d_in[18];
  const float* W_ni = (const float*)d_in[19]; const float* b_ni = (const float*)d_in[20];
  const float* W_ii = (const float*)d_in[21]; const float* b_ii = (const float*)d_in[22];
  const float* W_si = (const float*)d_in[23]; const float* b_si = (const float*)d_in[24];
  const float* W_is = (const float*)d_in[25]; const float* b_is = (const float*)d_in[26];
  const float* Wih0 = (const float*)d_in[27]; const float* Whh0 = (const float*)d_in[28];
  const float* bih0 = (const float*)d_in[29]; const float* bhh0 = (const float*)d_in[30];
  const float* Wih1 = (const float*)d_in[31]; const float* Whh1 = (const float*)d_in[32];
  const float* bih1 = (const float*)d_in[33]; const float* bhh1 = (const float*)d_in[34];

  float* out_feat = (float*)d_out;
  float* out_h = out_feat + (size_t)N_TOT_ * T_ * H_;  // +46,080,000

  // zero accumulated scratch
  zero_k<<<(OF_DEG_END + 24 + 255) / 256, 256, 0, stream>>>();

  // degrees + counts
  deg_cnt_k<<<(16000 + 255) / 256, 256, 0, stream>>>(sc_src, sc_dst, 16000, OF_OUTD_SC, OF_IND_SC, OI_CNT_SC);
  deg_cnt_k<<<(20000 + 255) / 256, 256, 0, stream>>>(in_src, in_dst, 20000, OF_OUTD_IN, OF_IND_IN, OI_CNT_IN);
  deg_cnt_k<<<(20000 + 255) / 256, 256, 0, stream>>>(ni_src, ni_dst, 20000, OF_OUTD_NI, OF_IND_NI, OI_CNT_NI);
  deg_cnt_k<<<(100000 + 255) / 256, 256, 0, stream>>>(ii_src, ii_dst, 100000, OF_OUTD_II, OF_IND_II, OI_CNT_II);
  deg_cnt_k<<<(20000 + 255) / 256, 256, 0, stream>>>(si_src, si_dst, 20000, OF_OUTD_SI, OF_IND_SI, OI_CNT_SI);
  deg_cnt_k<<<(20000 + 255) / 256, 256, 0, stream>>>(is_src, is_dst, 20000, OF_OUTD_IS, OF_IND_IS, OI_CNT_IS);
  rsqrt_deg_k<<<(OF_DEG_END + 255) / 256, 256, 0, stream>>>();

  // LSTM weight transposes into gate-interleaved [k][j][4] layout
  transpose_w2_k<<<(256 * 128 + 255) / 256, 256, 0, stream>>>(Wih0, OF_W0, 128);
  transpose_w2_k<<<(256 * 64 + 255) / 256, 256, 0, stream>>>(Whh0, OF_W0 + 128 * 256, 64);
  transpose_w2_k<<<(256 * 64 + 255) / 256, 256, 0, stream>>>(Wih1, OF_W1, 64);
  transpose_w2_k<<<(256 * 64 + 255) / 256, 256, 0, stream>>>(Whh1, OF_W1 + 64 * 256, 64);

  // CSR build
  exscan6_k<<<6, 256, 0, stream>>>();
  zero_cnt_k<<<(OI_CNT_END + 255) / 256, 256, 0, stream>>>();
  fill_csr_k<<<(20000 + 255) / 256, 256, 0, stream>>>(in_src, in_dst, 20000, OI_OFF_IN, OI_CNT_IN, OI_CSR_IN);
  fill_csr_k<<<(20000 + 255) / 256, 256, 0, stream>>>(ni_src, ni_dst, 20000, OI_OFF_NI, OI_CNT_NI, OI_CSR_NI);
  fill_csr_k<<<(100000 + 255) / 256, 256, 0, stream>>>(ii_src, ii_dst, 100000, OI_OFF_II, OI_CNT_II, OI_CSR_II);
  fill_csr_k<<<(20000 + 255) / 256, 256, 0, stream>>>(si_src, si_dst, 20000, OI_OFF_SI, OI_CNT_SI, OI_CSR_SI);
  fill_csr_k<<<(16000 + 255) / 256, 256, 0, stream>>>(sc_src, sc_dst, 16000, OI_OFF_SC, OI_CNT_SC, OI_CSR_SC);
  fill_csr_k<<<(20000 + 255) / 256, 256, 0, stream>>>(is_src, is_dst, 20000, OI_OFF_IS, OI_CNT_IS, OI_CSR_IS);

  // fused gather + GEMM per dst type
  gconv_gather_k<1><<<N_NODE_, 256, 0, stream>>>(
      x_pod, nullptr, nullptr, OI_OFF_IN, 0, 0, OI_CSR_IN, 0, 0,
      OF_OUTD_IN, 0, 0, OF_IND_IN, 0, 0,
      W_in, nullptr, nullptr, b_in, nullptr, nullptr, 1.0f, out_feat);
  gconv_gather_k<3><<<N_POD_, 256, 0, stream>>>(
      x_node, x_pod, x_svc, OI_OFF_NI, OI_OFF_II, OI_OFF_SI, OI_CSR_NI, OI_CSR_II, OI_CSR_SI,
      OF_OUTD_NI, OF_OUTD_II, OF_OUTD_SI, OF_IND_NI, OF_IND_II, OF_IND_SI,
      W_ni, W_ii, W_si, b_ni, b_ii, b_si, 1.0f / 3.0f,
      out_feat + (size_t)N_NODE_ * (T_ * H_));
  gconv_gather_k<2><<<N_SVC_, 256, 0, stream>>>(
      x_svc, x_pod, nullptr, OI_OFF_SC, OI_OFF_IS, 0, OI_CSR_SC, OI_CSR_IS, 0,
      OF_OUTD_SC, OF_OUTD_IS, 0, OF_IND_SC, OF_IND_IS, 0,
      W_sc, W_is, nullptr, b_sc, b_is, nullptr, 0.5f,
      out_feat + (size_t)(N_NODE_ + N_POD_) * (T_ * H_));

  // 2-layer LSTM: register-resident, readlane-broadcast, no LDS/barriers
  lstm_reg_k<<<512, 256, 0, stream>>>(
      out_feat, bih0, bhh0, bih1, bhh1, out_h);
}

// Round 3
// 1653.369 us; speedup vs baseline: 1.7137x; 1.0981x over previous
//
#include <hip/hip_runtime.h>

typedef unsigned int u32;

#define N_NODE_ 500
#define N_POD_  20000
#define N_SVC_  2000
#define N_TOT_  22500
#define T_ 16
#define F_ 64
#define H_ 128
#define O_ 64

// ---------------- static device scratch (no d_ws use) ----------------
// float region
#define OF_OUTD_SC  0
#define OF_IND_SC   2000
#define OF_OUTD_IN  4000
#define OF_IND_IN   24000
#define OF_OUTD_NI  24500
#define OF_IND_NI   25000
#define OF_OUTD_II  45000
#define OF_IND_II   65000
#define OF_OUTD_SI  85000
#define OF_IND_SI   87000
#define OF_OUTD_IS  107000
#define OF_IND_IS   127000
#define OF_DEG_END  129000
// LSTM weights, gate-interleaved transposed layout:
//   W[k][j][q] at offset k*256 + j*4 + q, value = W_orig[q*64 + j][k]
// OF_W0: [192][256]  (k<128: Wih0, k>=128: Whh0)
// OF_W1: [128][256]  (k<64:  Wih1, k>=64:  Whh1)
#define OF_W0       129024
#define OF_W1       (129024 + 49152)
#define G_F_SIZE    (129024 + 81920)
// int region (cnt doubles as fill cursor after re-zero)
#define OI_CNT_IN 0
#define OI_CNT_NI 500
#define OI_CNT_II 20500
#define OI_CNT_SI 40500
#define OI_CNT_SC 60500
#define OI_CNT_IS 62500
#define OI_CNT_END 64500
#define OI_OFF_IN 64500
#define OI_OFF_NI 65001
#define OI_OFF_II 85002
#define OI_OFF_SI 105003
#define OI_OFF_SC 125004
#define OI_OFF_IS 127005
#define OI_CSR_IN 129006
#define OI_CSR_NI 149006
#define OI_CSR_II 169006
#define OI_CSR_SI 269006
#define OI_CSR_SC 289006
#define OI_CSR_IS 305006
#define G_I_SIZE  325006

__device__ __align__(16) float g_f[G_F_SIZE];
__device__ int g_i[G_I_SIZE];

__device__ __forceinline__ float sigf(float x) { return 1.0f / (1.0f + __expf(-x)); }

// ---------- zero the accumulated scratch regions (every launch) ----------
__global__ void zero_k() {
  int i = blockIdx.x * 256 + threadIdx.x;
  if (i < OF_DEG_END + 24) g_f[i] = 0.0f;
  if (i < OI_CNT_END) g_i[i] = 0;
}

__global__ void zero_cnt_k() {
  int i = blockIdx.x * 256 + threadIdx.x;
  if (i < OI_CNT_END) g_i[i] = 0;
}

// ---------- per-relation degrees + in-counts ----------
__global__ void deg_cnt_k(const int* __restrict__ src, const int* __restrict__ dst, int n,
                          int o_outd, int o_ind, int o_cnt) {
  int e = blockIdx.x * 256 + threadIdx.x;
  if (e < n) {
    atomicAdd(&g_f[o_outd + src[e]], 1.0f);
    atomicAdd(&g_f[o_ind + dst[e]], 1.0f);
    atomicAdd(&g_i[o_cnt + dst[e]], 1);
  }
}

__global__ void rsqrt_deg_k() {
  int i = blockIdx.x * 256 + threadIdx.x;
  if (i < OF_DEG_END) g_f[i] = rsqrtf(fmaxf(g_f[i], 1.0f));
}

// fp32 [256,K] (gate-major rows: i,f,g,o blocks of 64) -> gate-interleaved [K][64][4]
__global__ void transpose_w2_k(const float* __restrict__ in, int o_out, int K) {
  int i = blockIdx.x * 256 + threadIdx.x;
  if (i < 256 * K) {
    int r = i / K, k = i - r * K;
    int q = r >> 6, j = r & 63;
    g_f[o_out + k * 256 + (j << 2) + q] = in[i];
  }
}

// ---------- 6 single-block exclusive scans ----------
__global__ void exscan6_k() {
  const int cnto[6] = {OI_CNT_IN, OI_CNT_NI, OI_CNT_II, OI_CNT_SI, OI_CNT_SC, OI_CNT_IS};
  const int offo[6] = {OI_OFF_IN, OI_OFF_NI, OI_OFF_II, OI_OFF_SI, OI_OFF_SC, OI_OFF_IS};
  const int ns[6] = {500, 20000, 20000, 20000, 2000, 2000};
  int rel = blockIdx.x;
  const int* cnt = g_i + cnto[rel];
  int* off = g_i + offo[rel];
  int n = ns[rel];
  __shared__ int base_s[257];
  __shared__ int part[256];
  int tid = threadIdx.x;
  int chunk = (n + 255) >> 8;
  int lo = tid * chunk;
  int hi = lo + chunk; if (hi > n) hi = n;
  int s = 0;
  for (int i = lo; i < hi; ++i) s += cnt[i];
  part[tid] = s;
  __syncthreads();
  if (tid == 0) {
    int run = 0;
    for (int j = 0; j < 256; ++j) { base_s[j] = run; run += part[j]; }
    base_s[256] = run;
  }
  __syncthreads();
  int run = base_s[tid];
  for (int i = lo; i < hi; ++i) { off[i] = run; run += cnt[i]; }
  if (tid == 0) off[n] = base_s[256];
}

__global__ void fill_csr_k(const int* __restrict__ src, const int* __restrict__ dst, int n,
                           int o_off, int o_cur, int o_csr) {
  int e = blockIdx.x * 256 + threadIdx.x;
  if (e < n) {
    int d = dst[e];
    int p = atomicAdd(&g_i[o_cur + d], 1);
    g_i[o_csr + g_i[o_off + d] + p] = src[e];
  }
}

// ---------- fused gather + GEMM per dst node ----------
// block = one dst node; 256 threads; out[t][h] = relu(scale*(sum_rel m_rel*rsqrt(ind)*W_rel + b_rel))
template <int NREL>
__global__ __launch_bounds__(256) void gconv_gather_k(
    const float* __restrict__ x0, const float* __restrict__ x1, const float* __restrict__ x2,
    int off0, int off1, int off2, int csr0, int csr1, int csr2,
    int od0, int od1, int od2, int id0, int id1, int id2,
    const float* __restrict__ W0, const float* __restrict__ W1, const float* __restrict__ W2,
    const float* __restrict__ b0, const float* __restrict__ b1, const float* __restrict__ b2,
    float scale, float* __restrict__ outp) {
  const float* xs_[3] = {x0, x1, x2};
  const int offs[3] = {off0, off1, off2};
  const int csrs[3] = {csr0, csr1, csr2};
  const int ods[3] = {od0, od1, od2};
  const int ids[3] = {id0, id1, id2};
  const float* Ws[3] = {W0, W1, W2};
  const float* bs[3] = {b0, b1, b2};

  int node = blockIdx.x;
  int tid = threadIdx.x;
  int c = tid & 127;
  int rg = tid >> 7;  // 0/1 -> t rows [0,8) / [8,16)
  __shared__ float msh[T_][F_];  // flat index = t*64+f

  float bb = 0.0f;
#pragma unroll
  for (int rel = 0; rel < NREL; ++rel) bb += bs[rel][c];
  float acc[8];
#pragma unroll
  for (int i = 0; i < 8; ++i) acc[i] = bb;

#pragma unroll
  for (int rel = 0; rel < NREL; ++rel) {
    int e0 = g_i[offs[rel] + node], e1 = g_i[offs[rel] + node + 1];
    const int* csr = g_i + csrs[rel];
    const float* od = g_f + ods[rel];
    const float* xr = xs_[rel];
    // thread owns 4 contiguous elements of the 1024-float [T,F] row
    float a0 = 0.0f, a1 = 0.0f, a2 = 0.0f, a3 = 0.0f;
    for (int e = e0; e < e1; ++e) {
      int s = csr[e];
      float rs = od[s];
      float4 v = ((const float4*)(xr + (size_t)s * 1024))[tid];
      a0 += v.x * rs;
      a1 += v.y * rs;
      a2 += v.z * rs;
      a3 += v.w * rs;
    }
    __syncthreads();  // previous rel's GEMM reads done
    float* mf = &msh[0][0];
    mf[tid * 4 + 0] = a0;
    mf[tid * 4 + 1] = a1;
    mf[tid * 4 + 2] = a2;
    mf[tid * 4 + 3] = a3;
    __syncthreads();
    float rind = g_f[ids[rel] + node];
    const float* W = Ws[rel];
#pragma unroll 4
    for (int f = 0; f < F_; ++f) {
      float w = W[f * H_ + c] * rind;
#pragma unroll
      for (int i = 0; i < 8; ++i) acc[i] += msh[rg * 8 + i][f] * w;
    }
  }
  float* o = outp + (size_t)node * (T_ * H_);
#pragma unroll
  for (int i = 0; i < 8; ++i) {
    float v = acc[i] * scale;
    o[(rg * 8 + i) * H_ + c] = fmaxf(v, 0.0f);
  }
}

// ---------- 2-layer LSTM: LDS-broadcast, wave-private, barrier-free ----------
// Grid: 512 blocks x 256 threads (4 waves), RW=11 rows per wave (512*4*11=22528).
// Exactly 2 blocks/CU, 2 waves/SIMD. Lane l owns hidden unit l (all 4 gates).
// Row-broadcast operands live in a wave-PRIVATE LDS slice xh[r][256]:
//   [0:128) = x_t, [128:192) = h0, [192:256) = h1
// so layer 0 consumes k=0..192 contiguously (matches [Wih0|Whh0] layout) and
// layer 1 consumes k=128..256 contiguously (matches [Wih1|Whh1] layout).
// Broadcast = uniform-address ds_read_b128 (free broadcast, 4 k per instr,
// 16 FMAs per read) - replaces v_readlane (~12 cyc each, half of round-2's
// VALU time). No __syncthreads anywhere (regions are wave-private; in-wave
// DS ordering is by program order + compiler waitcnts).
#define RW 11

__device__ __forceinline__ void gemv_lds(float acc[RW][4], const float* xrow0,
                                         const float4* __restrict__ Wb, int nk4, int l) {
#pragma unroll 2
  for (int k4 = 0; k4 < nk4; ++k4) {
    const float4* wp = Wb + (k4 << 8) + l;  // 4 consecutive k rows of [64]float4
    float4 w0 = wp[0];
    float4 w1 = wp[64];
    float4 w2 = wp[128];
    float4 w3 = wp[192];
#pragma unroll
    for (int r = 0; r < RW; ++r) {
      float4 xv = *(const float4*)(xrow0 + r * 256 + k4 * 4);  // ds_read_b128, uniform addr
      acc[r][0] += xv.x * w0.x; acc[r][1] += xv.x * w0.y; acc[r][2] += xv.x * w0.z; acc[r][3] += xv.x * w0.w;
      acc[r][0] += xv.y * w1.x; acc[r][1] += xv.y * w1.y; acc[r][2] += xv.y * w1.z; acc[r][3] += xv.y * w1.w;
      acc[r][0] += xv.z * w2.x; acc[r][1] += xv.z * w2.y; acc[r][2] += xv.z * w2.z; acc[r][3] += xv.z * w2.w;
      acc[r][0] += xv.w * w3.x; acc[r][1] += xv.w * w3.y; acc[r][2] += xv.w * w3.z; acc[r][3] += xv.w * w3.w;
    }
  }
}

__global__ __launch_bounds__(256, 2) void lstm_lds_k(
    const float* __restrict__ feat,  // [N_TOT,16,128] fp32 (post-relu)
    const float* __restrict__ bih0, const float* __restrict__ bhh0,
    const float* __restrict__ bih1, const float* __restrict__ bhh1,
    float* __restrict__ out2) {
  const float4* W0v = (const float4*)(g_f + OF_W0);  // [192][64] float4
  const float4* W1v = (const float4*)(g_f + OF_W1);  // [128][64] float4
  __shared__ __align__(16) float xh[4][RW][256];     // 45056 B
  int tid = threadIdx.x;
  int l = tid & 63;
  int wid = tid >> 6;
  int row0 = (blockIdx.x * 4 + wid) * RW;
  float* xw = &xh[wid][0][0];

  float bb0[4], bb1[4];
#pragma unroll
  for (int q = 0; q < 4; ++q) {
    bb0[q] = bih0[q * 64 + l] + bhh0[q * 64 + l];
    bb1[q] = bih1[q * 64 + l] + bhh1[q * 64 + l];
  }

  const float* xb[RW];
  bool vld[RW];
#pragma unroll
  for (int r = 0; r < RW; ++r) {
    int row = row0 + r;
    vld[r] = row < N_TOT_;
    xb[r] = feat + (size_t)(vld[r] ? row : 0) * (T_ * H_);
  }

  float c0[RW] = {}, c1[RW] = {};
  // zero h0/h1 regions (wave-private, no barrier needed)
#pragma unroll
  for (int r = 0; r < RW; ++r) {
    xw[r * 256 + 128 + l] = 0.0f;
    xw[r * 256 + 192 + l] = 0.0f;
  }

  for (int t = 0; t < T_; ++t) {
    // stage x_t into the wave's LDS slice (coalesced global, linear LDS)
#pragma unroll
    for (int r = 0; r < RW; ++r) {
      xw[r * 256 + l] = xb[r][t * H_ + l];
      xw[r * 256 + 64 + l] = xb[r][t * H_ + 64 + l];
    }

    float acc[RW][4];
#pragma unroll
    for (int r = 0; r < RW; ++r)
#pragma unroll
      for (int q = 0; q < 4; ++q) acc[r][q] = bb0[q];

    // layer 0: [x_t | h0_prev] @ [Wih0 | Whh0], K=192 contiguous in LDS
    gemv_lds(acc, xw, W0v, 48, l);

#pragma unroll
    for (int r = 0; r < RW; ++r) {
      float iv = sigf(acc[r][0]);
      float fv = sigf(acc[r][1]);
      float gv = tanhf(acc[r][2]);
      float ov = sigf(acc[r][3]);
      float cc = fv * c0[r] + iv * gv;
      c0[r] = cc;
      xw[r * 256 + 128 + l] = ov * tanhf(cc);  // h0_new -> LDS
    }

#pragma unroll
    for (int r = 0; r < RW; ++r)
#pragma unroll
      for (int q = 0; q < 4; ++q) acc[r][q] = bb1[q];

    // layer 1: [h0_new | h1_prev] @ [Wih1 | Whh1], K=128 contiguous in LDS
    gemv_lds(acc, xw + 128, W1v, 32, l);

#pragma unroll
    for (int r = 0; r < RW; ++r) {
      float iv = sigf(acc[r][0]);
      float fv = sigf(acc[r][1]);
      float gv = tanhf(acc[r][2]);
      float ov = sigf(acc[r][3]);
      float cc = fv * c1[r] + iv * gv;
      c1[r] = cc;
      float hh = ov * tanhf(cc);
      xw[r * 256 + 192 + l] = hh;  // h1_new -> LDS
      if (vld[r]) out2[((size_t)(row0 + r) * T_ + t) * O_ + l] = fmaxf(hh, 0.0f);
    }
  }
}

extern "C" void kernel_launch(void* const* d_in, const int* in_sizes, int n_in,
                              void* d_out, int out_size, void* d_ws, size_t ws_size,
                              hipStream_t stream) {
  (void)in_sizes; (void)n_in; (void)out_size; (void)d_ws; (void)ws_size;
  const float* x_node = (const float*)d_in[0];
  const float* x_pod  = (const float*)d_in[1];
  const float* x_svc  = (const float*)d_in[2];
  const int* sc_src = (const int*)d_in[3];
  const int* sc_dst = (const int*)d_in[4];
  const int* in_src = (const int*)d_in[5];
  const int* in_dst = (const int*)d_in[6];
  const int* ni_src = (const int*)d_in[7];
  const int* ni_dst = (const int*)d_in[8];
  const int* ii_src = (const int*)d_in[9];
  const int* ii_dst = (const int*)d_in[10];
  const int* si_src = (const int*)d_in[11];
  const int* si_dst = (const int*)d_in[12];
  const int* is_src = (const int*)d_in[13];
  const int* is_dst = (const int*)d_in[14];
  const float* W_sc = (const float*)d_in[15]; const float* b_sc = (const float*)d_in[16];
  const float* W_in = (const float*)d_in[17]; const float* b_in = (const float*)d_in[18];
  const float* W_ni = (const float*)d_in[19]; const float* b_ni = (const float*)d_in[20];
  const float* W_ii = (const float*)d_in[21]; const float* b_ii = (const float*)d_in[22];
  const float* W_si = (const float*)d_in[23]; const float* b_si = (const float*)d_in[24];
  const float* W_is = (const float*)d_in[25]; const float* b_is = (const float*)d_in[26];
  const float* Wih0 = (const float*)d_in[27]; const float* Whh0 = (const float*)d_in[28];
  const float* bih0 = (const float*)d_in[29]; const float* bhh0 = (const float*)d_in[30];
  const float* Wih1 = (const float*)d_in[31]; const float* Whh1 = (const float*)d_in[32];
  const float* bih1 = (const float*)d_in[33]; const float* bhh1 = (const float*)d_in[34];

  float* out_feat = (float*)d_out;
  float* out_h = out_feat + (size_t)N_TOT_ * T_ * H_;  // +46,080,000

  // zero accumulated scratch
  zero_k<<<(OF_DEG_END + 24 + 255) / 256, 256, 0, stream>>>();

  // degrees + counts
  deg_cnt_k<<<(16000 + 255) / 256, 256, 0, stream>>>(sc_src, sc_dst, 16000, OF_OUTD_SC, OF_IND_SC, OI_CNT_SC);
  deg_cnt_k<<<(20000 + 255) / 256, 256, 0, stream>>>(in_src, in_dst, 20000, OF_OUTD_IN, OF_IND_IN, OI_CNT_IN);
  deg_cnt_k<<<(20000 + 255) / 256, 256, 0, stream>>>(ni_src, ni_dst, 20000, OF_OUTD_NI, OF_IND_NI, OI_CNT_NI);
  deg_cnt_k<<<(100000 + 255) / 256, 256, 0, stream>>>(ii_src, ii_dst, 100000, OF_OUTD_II, OF_IND_II, OI_CNT_II);
  deg_cnt_k<<<(20000 + 255) / 256, 256, 0, stream>>>(si_src, si_dst, 20000, OF_OUTD_SI, OF_IND_SI, OI_CNT_SI);
  deg_cnt_k<<<(20000 + 255) / 256, 256, 0, stream>>>(is_src, is_dst, 20000, OF_OUTD_IS, OF_IND_IS, OI_CNT_IS);
  rsqrt_deg_k<<<(OF_DEG_END + 255) / 256, 256, 0, stream>>>();

  // LSTM weight transposes into gate-interleaved [k][j][4] layout
  transpose_w2_k<<<(256 * 128 + 255) / 256, 256, 0, stream>>>(Wih0, OF_W0, 128);
  transpose_w2_k<<<(256 * 64 + 255) / 256, 256, 0, stream>>>(Whh0, OF_W0 + 128 * 256, 64);
  transpose_w2_k<<<(256 * 64 + 255) / 256, 256, 0, stream>>>(Wih1, OF_W1, 64);
  transpose_w2_k<<<(256 * 64 + 255) / 256, 256, 0, stream>>>(Whh1, OF_W1 + 64 * 256, 64);

  // CSR build
  exscan6_k<<<6, 256, 0, stream>>>();
  zero_cnt_k<<<(OI_CNT_END + 255) / 256, 256, 0, stream>>>();
  fill_csr_k<<<(20000 + 255) / 256, 256, 0, stream>>>(in_src, in_dst, 20000, OI_OFF_IN, OI_CNT_IN, OI_CSR_IN);
  fill_csr_k<<<(20000 + 255) / 256, 256, 0, stream>>>(ni_src, ni_dst, 20000, OI_OFF_NI, OI_CNT_NI, OI_CSR_NI);
  fill_csr_k<<<(100000 + 255) / 256, 256, 0, stream>>>(ii_src, ii_dst, 100000, OI_OFF_II, OI_CNT_II, OI_CSR_II);
  fill_csr_k<<<(20000 + 255) / 256, 256, 0, stream>>>(si_src, si_dst, 20000, OI_OFF_SI, OI_CNT_SI, OI_CSR_SI);
  fill_csr_k<<<(16000 + 255) / 256, 256, 0, stream>>>(sc_src, sc_dst, 16000, OI_OFF_SC, OI_CNT_SC, OI_CSR_SC);
  fill_csr_k<<<(20000 + 255) / 256, 256, 0, stream>>>(is_src, is_dst, 20000, OI_OFF_IS, OI_CNT_IS, OI_CSR_IS);

  // fused gather + GEMM per dst type
  gconv_gather_k<1><<<N_NODE_, 256, 0, stream>>>(
      x_pod, nullptr, nullptr, OI_OFF_IN, 0, 0, OI_CSR_IN, 0, 0,
      OF_OUTD_IN, 0, 0, OF_IND_IN, 0, 0,
      W_in, nullptr, nullptr, b_in, nullptr, nullptr, 1.0f, out_feat);
  gconv_gather_k<3><<<N_POD_, 256, 0, stream>>>(
      x_node, x_pod, x_svc, OI_OFF_NI, OI_OFF_II, OI_OFF_SI, OI_CSR_NI, OI_CSR_II, OI_CSR_SI,
      OF_OUTD_NI, OF_OUTD_II, OF_OUTD_SI, OF_IND_NI, OF_IND_II, OF_IND_SI,
      W_ni, W_ii, W_si, b_ni, b_ii, b_si, 1.0f / 3.0f,
      out_feat + (size_t)N_NODE_ * (T_ * H_));
  gconv_gather_k<2><<<N_SVC_, 256, 0, stream>>>(
      x_svc, x_pod, nullptr, OI_OFF_SC, OI_OFF_IS, 0, OI_CSR_SC, OI_CSR_IS, 0,
      OF_OUTD_SC, OF_OUTD_IS, 0, OF_IND_SC, OF_IND_IS, 0,
      W_sc, W_is, nullptr, b_sc, b_is, nullptr, 0.5f,
      out_feat + (size_t)(N_NODE_ + N_POD_) * (T_ * H_));

  // 2-layer LSTM: LDS-broadcast, wave-private, barrier-free
  lstm_lds_k<<<512, 256, 0, stream>>>(
      out_feat, bih0, bhh0, bih1, bhh1, out_h);
}